// Round 9
// baseline (133.964 us; speedup 1.0000x reference)
//
#include <hip/hip_runtime.h>
#include <math.h>

#define BT 1024
#define BN 1024
#define D  256
#define H  8
#define DH 32

typedef __attribute__((ext_vector_type(8))) short short8;
typedef __attribute__((ext_vector_type(4))) float f32x4;

__device__ __forceinline__ unsigned short f2bf(float x) {
  union { float f; unsigned int u; } v; v.f = x;
  unsigned int r = v.u + 0x7fffu + ((v.u >> 16) & 1u);
  return (unsigned short)(r >> 16);
}
__device__ __forceinline__ float bf2f(unsigned short u) {
  union { unsigned int u; float f; } v; v.u = ((unsigned int)u) << 16;
  return v.f;
}
__device__ __forceinline__ unsigned pack2(float a, float b) {
  return (unsigned)f2bf(a) | ((unsigned)f2bf(b) << 16);
}

// ===========================================================================
// Dispatch 1: blocks [0,768)    qkv GEMMs (fp32->bf16 in LDS staging)
//             blocks [768,1024) tag pack row-major: tags[row][n]=adj?et:2 (u8)
//             blocks [1024,1040) ek/ev = E @ {Wk,Wv}^T
//             blocks [1040,1056) Wo fp32 -> bf16
// ===========================================================================
__global__ __launch_bounds__(256) void fused_prep_qkv(
    const float* __restrict__ ht, const float* __restrict__ hn,
    const int* __restrict__ adj, const int* __restrict__ ety,
    const float* __restrict__ Wq, const float* __restrict__ bq,
    const float* __restrict__ Wk, const float* __restrict__ bk,
    const float* __restrict__ Wv, const float* __restrict__ bv,
    const float* __restrict__ Wo, const float* __restrict__ E,
    unsigned char* __restrict__ tags, float* __restrict__ ek,
    float* __restrict__ ev, unsigned short* __restrict__ Qh,
    unsigned short* __restrict__ Kh, unsigned short* __restrict__ Vt,
    unsigned short* __restrict__ Wob) {
  const int blk = blockIdx.x;
  const int tid = threadIdx.x;

  if (blk < 768) {
    const int gm = blk >> 8;           // 0=Q, 1=K, 2=V
    const int rem = blk & 255;
    const int m0 = (rem & 63) * 16;
    const int nb0 = (rem >> 6) * 64;
    const float* X = (gm == 0) ? ht : hn;
    const float* W = (gm == 0) ? Wq : (gm == 1) ? Wk : Wv;
    const float* bias = (gm == 0) ? bq : (gm == 1) ? bk : bv;

    __shared__ unsigned short als[16][264];
    __shared__ unsigned short bls[64][264];

    const int c = (tid & 15) * 16;
    {
      int row = tid >> 4;
      const float* s = X + (size_t)(m0 + row) * D + c;
      uint4 u0, u1;
      float4 f;
      f = *(const float4*)(s + 0);  u0.x = pack2(f.x, f.y); u0.y = pack2(f.z, f.w);
      f = *(const float4*)(s + 4);  u0.z = pack2(f.x, f.y); u0.w = pack2(f.z, f.w);
      f = *(const float4*)(s + 8);  u1.x = pack2(f.x, f.y); u1.y = pack2(f.z, f.w);
      f = *(const float4*)(s + 12); u1.z = pack2(f.x, f.y); u1.w = pack2(f.z, f.w);
      *(uint4*)&als[row][c] = u0;
      *(uint4*)&als[row][c + 8] = u1;
    }
#pragma unroll
    for (int j = 0; j < 4; ++j) {
      int row = j * 16 + (tid >> 4);
      const float* s = W + (size_t)(nb0 + row) * D + c;
      uint4 u0, u1;
      float4 f;
      f = *(const float4*)(s + 0);  u0.x = pack2(f.x, f.y); u0.y = pack2(f.z, f.w);
      f = *(const float4*)(s + 4);  u0.z = pack2(f.x, f.y); u0.w = pack2(f.z, f.w);
      f = *(const float4*)(s + 8);  u1.x = pack2(f.x, f.y); u1.y = pack2(f.z, f.w);
      f = *(const float4*)(s + 12); u1.z = pack2(f.x, f.y); u1.w = pack2(f.z, f.w);
      *(uint4*)&bls[row][c] = u0;
      *(uint4*)&bls[row][c + 8] = u1;
    }
    __syncthreads();

    const int lane = tid & 63, wid = tid >> 6;
    const int quad = lane >> 4, l16 = lane & 15;
    f32x4 acc0 = {0.f, 0.f, 0.f, 0.f};
    f32x4 acc1 = {0.f, 0.f, 0.f, 0.f};
#pragma unroll
    for (int k0 = 0; k0 < 128; k0 += 32) {
      short8 a = *(const short8*)&als[l16][k0 + quad * 8];
      short8 b = *(const short8*)&bls[wid * 16 + l16][k0 + quad * 8];
      acc0 = __builtin_amdgcn_mfma_f32_16x16x32_bf16(a, b, acc0, 0, 0, 0);
    }
#pragma unroll
    for (int k0 = 128; k0 < 256; k0 += 32) {
      short8 a = *(const short8*)&als[l16][k0 + quad * 8];
      short8 b = *(const short8*)&bls[wid * 16 + l16][k0 + quad * 8];
      acc1 = __builtin_amdgcn_mfma_f32_16x16x32_bf16(a, b, acc1, 0, 0, 0);
    }
    f32x4 acc = acc0 + acc1;

    const int col = nb0 + wid * 16 + l16;
    const float bia = bias[col];
    const int h = col >> 5, d = col & 31;
    if (gm == 2) {
      uint2 o;
      o.x = pack2(acc[0] + bia, acc[1] + bia);
      o.y = pack2(acc[2] + bia, acc[3] + bia);
      *(uint2*)(Vt + (size_t)h * 32768 + (size_t)d * 1024 + m0 + quad * 4) = o;
    } else {
      unsigned short* dst = (gm == 0) ? Qh : Kh;
#pragma unroll
      for (int r = 0; r < 4; ++r) {
        int row = m0 + quad * 4 + r;
        dst[(size_t)h * 32768 + (size_t)row * 32 + d] = f2bf(acc[r] + bia);
      }
    }
  } else if (blk < 1024) {
    const int local = blk - 768;
#pragma unroll
    for (int i = 0; i < 4; ++i) {
      int idx = local * 1024 + i * 256 + tid;  // int4 units
      int4 a = ((const int4*)adj)[idx];
      int4 t = ((const int4*)ety)[idx];
      uchar4 o;
      o.x = a.x ? (unsigned char)t.x : (unsigned char)2;
      o.y = a.y ? (unsigned char)t.y : (unsigned char)2;
      o.z = a.z ? (unsigned char)t.z : (unsigned char)2;
      o.w = a.w ? (unsigned char)t.w : (unsigned char)2;
      ((uchar4*)tags)[idx] = o;
    }
  } else if (blk < 1040) {
    const int g = blk - 1024;
    const int bx = g & 7, by = g >> 3;
    const int c = tid >> 3, kseg = tid & 7;
    const int col = bx * 32 + c;
    const float* W = by ? Wv : Wk;
    float* outp = by ? ev : ek;
    const float* wrow = W + (size_t)col * D + kseg * 32;
    const float* e0p = E + kseg * 32;
    const float* e1p = E + D + kseg * 32;
    float p0 = 0.f, p1 = 0.f;
#pragma unroll
    for (int i = 0; i < 8; ++i) {
      float4 w4 = *(const float4*)(wrow + i * 4);
      float4 a4 = *(const float4*)(e0p + i * 4);
      float4 b4 = *(const float4*)(e1p + i * 4);
      p0 += w4.x * a4.x + w4.y * a4.y + w4.z * a4.z + w4.w * a4.w;
      p1 += w4.x * b4.x + w4.y * b4.y + w4.z * b4.z + w4.w * b4.w;
    }
#pragma unroll
    for (int off = 1; off <= 4; off <<= 1) {
      p0 += __shfl_xor(p0, off);
      p1 += __shfl_xor(p1, off);
    }
    if (kseg == 0) { outp[col] = p0; outp[D + col] = p1; }
  } else {
    const int g = blk - 1040;
    const int base = g * 4096;
#pragma unroll
    for (int half = 0; half < 2; ++half) {
      int e0 = base + half * 2048 + tid * 8;
      float4 f0 = *(const float4*)(Wo + e0);
      float4 f1 = *(const float4*)(Wo + e0 + 4);
      uint4 o;
      o.x = pack2(f0.x, f0.y);
      o.y = pack2(f0.z, f0.w);
      o.z = pack2(f1.x, f1.y);
      o.w = pack2(f1.z, f1.w);
      *(uint4*)(Wob + e0) = o;
    }
  }
}

// ===========================================================================
// Dispatch 2: attention + output projection fused, no grid sync needed.
// Block = 16 target rows x ALL 8 heads. 64 blocks x 1024 threads (16 waves).
// Wave w: head h = w>>1, neighbor half = w&1 (512 neighbors, 16 chunks of 32).
// Main loop is R8's barrier-free transposed-score scheme (per-wave LDS P).
// Then: wave-pair combine (1 barrier) -> epilogue into LDS Ob tile (bf16)
// -> 1 barrier -> 16 waves do the 16x256 output projection (A from LDS,
// B = Wob global), fp32 stores. Zero global Ob roundtrip.
// ===========================================================================
__global__ __launch_bounds__(1024, 1) void attn_proj(
    const unsigned short* __restrict__ Qh, const unsigned short* __restrict__ Kh,
    const unsigned short* __restrict__ Vt,
    const float* __restrict__ ek, const float* __restrict__ ev,
    const unsigned char* __restrict__ tags, const unsigned short* __restrict__ Wob,
    const float* __restrict__ bo, float* __restrict__ out) {
  __shared__ __align__(16) unsigned short P[16][16][40];  // per-wave, 20480 B
  __shared__ float comb[8][640];                          // pair combine, 20480 B
  __shared__ unsigned short obls[16][264];                // Ob tile, 8448 B

  const int row0 = blockIdx.x * 16;
  const int tid = threadIdx.x;
  const int w = tid >> 6;
  const int h = w >> 1;
  const int half = w & 1;
  const int lane = tid & 63;
  const int q = lane >> 4, l16 = lane & 15;
  const float scale = 0.17677669529663687f;  // 1/sqrt(32)

  const unsigned short* Qbase = Qh + (size_t)h * 32768;
  const unsigned short* Kbase = Kh + (size_t)h * 32768;
  const unsigned short* Vbase = Vt + (size_t)h * 32768;

  // B-operand: Q fragment (lane j=l16 -> target row, k=q*8 within head dims)
  short8 bQ = *(const short8*)(Qbase + (size_t)(row0 + l16) * 32 + q * 8);

  // qe[row][tg] redundantly per wave
  float qe_mine = 0.f;
  {
    int r = (lane >> 1) & 15, tg = lane & 1;
    const unsigned short* qp = Qbase + (size_t)(row0 + r) * 32;
    const float* ep = ek + tg * D + h * DH;
#pragma unroll
    for (int dd = 0; dd < 32; ++dd) qe_mine += bf2f(qp[dd]) * ep[dd];
    qe_mine *= scale;
  }
  const float qe0 = __shfl(qe_mine, l16 * 2, 64);
  const float qe1 = __shfl(qe_mine, l16 * 2 + 1, 64);

  float den_loc = 0.f, s1_loc = 0.f;
  f32x4 acc0 = {0.f, 0.f, 0.f, 0.f};
  f32x4 acc1 = {0.f, 0.f, 0.f, 0.f};
  const f32x4 zero = {0.f, 0.f, 0.f, 0.f};
  unsigned short* Pw = &P[w][0][0];

  for (int cch = 0; cch < 16; ++cch) {
    const int nb = half * 512 + cch * 32;
    short8 aK0 = *(const short8*)(Kbase + (size_t)(nb + l16) * 32 + q * 8);
    short8 aK1 = *(const short8*)(Kbase + (size_t)(nb + 16 + l16) * 32 + q * 8);
    short8 vA0 = *(const short8*)(Vbase + (size_t)l16 * 1024 + nb + q * 8);
    short8 vA1 = *(const short8*)(Vbase + (size_t)(16 + l16) * 1024 + nb + q * 8);
    uchar4 t0 = *(const uchar4*)(tags + (size_t)(row0 + l16) * BN + nb + q * 4);
    uchar4 t1 = *(const uchar4*)(tags + (size_t)(row0 + l16) * BN + nb + 16 + q * 4);

    f32x4 sc0 = __builtin_amdgcn_mfma_f32_16x16x32_bf16(aK0, bQ, zero, 0, 0, 0);
    f32x4 sc1 = __builtin_amdgcn_mfma_f32_16x16x32_bf16(aK1, bQ, zero, 0, 0, 0);

    const unsigned char ta0[4] = {t0.x, t0.y, t0.z, t0.w};
    const unsigned char ta1[4] = {t1.x, t1.y, t1.z, t1.w};
    float e0[4], e1[4];
#pragma unroll
    for (int r = 0; r < 4; ++r) {
      const int tg = ta0[r];
      float e = 0.f;
      if (tg != 2) e = __expf(fmaf(sc0[r], scale, tg ? qe1 : qe0));
      e0[r] = e;
      den_loc += e;
      s1_loc += (tg == 1) ? e : 0.f;
    }
#pragma unroll
    for (int r = 0; r < 4; ++r) {
      const int tg = ta1[r];
      float e = 0.f;
      if (tg != 2) e = __expf(fmaf(sc1[r], scale, tg ? qe1 : qe0));
      e1[r] = e;
      den_loc += e;
      s1_loc += (tg == 1) ? e : 0.f;
    }
    uint2 w0, w1;
    w0.x = pack2(e0[0], e0[1]); w0.y = pack2(e0[2], e0[3]);
    w1.x = pack2(e1[0], e1[1]); w1.y = pack2(e1[2], e1[3]);
    *(uint2*)&Pw[l16 * 40 + q * 4] = w0;
    *(uint2*)&Pw[l16 * 40 + 16 + q * 4] = w1;
    short8 pB = *(const short8*)&Pw[l16 * 40 + q * 8];
    acc0 = __builtin_amdgcn_mfma_f32_16x16x32_bf16(vA0, pB, acc0, 0, 0, 0);
    acc1 = __builtin_amdgcn_mfma_f32_16x16x32_bf16(vA1, pB, acc1, 0, 0, 0);
  }

  // den/s1 quad reduce -> all lanes hold row=l16 totals for this wave's half
  den_loc += __shfl_xor(den_loc, 16);
  den_loc += __shfl_xor(den_loc, 32);
  s1_loc += __shfl_xor(s1_loc, 16);
  s1_loc += __shfl_xor(s1_loc, 32);

  // ---- wave-pair combine ----
  if (half == 1) {
    float* cw = &comb[h][lane * 10];
    cw[0] = acc0[0]; cw[1] = acc0[1]; cw[2] = acc0[2]; cw[3] = acc0[3];
    cw[4] = acc1[0]; cw[5] = acc1[1]; cw[6] = acc1[2]; cw[7] = acc1[3];
    cw[8] = den_loc; cw[9] = s1_loc;
  }
  __syncthreads();
  if (half == 0) {
    const float* cr = &comb[h][lane * 10];
    acc0[0] += cr[0]; acc0[1] += cr[1]; acc0[2] += cr[2]; acc0[3] += cr[3];
    acc1[0] += cr[4]; acc1[1] += cr[5]; acc1[2] += cr[6]; acc1[3] += cr[7];
    const float dn = den_loc + cr[8];
    const float s1 = s1_loc + cr[9];
    const float s0 = dn - s1;
    const float inv = dn > 0.f ? 1.f / dn : 0.f;
    const float4 ev0a = *(const float4*)(ev + h * DH + q * 4);
    const float4 ev1a = *(const float4*)(ev + D + h * DH + q * 4);
    const float4 ev0b = *(const float4*)(ev + h * DH + 16 + q * 4);
    const float4 ev1b = *(const float4*)(ev + D + h * DH + 16 + q * 4);
    float oa[4], ob[4];
    oa[0] = (acc0[0] + s1 * ev1a.x + s0 * ev0a.x) * inv;
    oa[1] = (acc0[1] + s1 * ev1a.y + s0 * ev0a.y) * inv;
    oa[2] = (acc0[2] + s1 * ev1a.z + s0 * ev0a.z) * inv;
    oa[3] = (acc0[3] + s1 * ev1a.w + s0 * ev0a.w) * inv;
    ob[0] = (acc1[0] + s1 * ev1b.x + s0 * ev0b.x) * inv;
    ob[1] = (acc1[1] + s1 * ev1b.y + s0 * ev0b.y) * inv;
    ob[2] = (acc1[2] + s1 * ev1b.z + s0 * ev0b.z) * inv;
    ob[3] = (acc1[3] + s1 * ev1b.w + s0 * ev0b.w) * inv;
    uint2 u0, u1;
    u0.x = pack2(oa[0], oa[1]); u0.y = pack2(oa[2], oa[3]);
    u1.x = pack2(ob[0], ob[1]); u1.y = pack2(ob[2], ob[3]);
    *(uint2*)&obls[l16][h * 32 + q * 4] = u0;        // d = q*4..q*4+3
    *(uint2*)&obls[l16][h * 32 + 16 + q * 4] = u1;   // d = 16+q*4..
  }
  __syncthreads();

  // ---- output projection: wave w -> cols [w*16, w*16+16), K = 256 ----
  {
    const int n0 = w * 16;
    f32x4 pa0 = {0.f, 0.f, 0.f, 0.f};
    f32x4 pa1 = {0.f, 0.f, 0.f, 0.f};
#pragma unroll
    for (int k0 = 0; k0 < 128; k0 += 32) {
      short8 a = *(const short8*)&obls[l16][k0 + q * 8];
      short8 b = *(const short8*)(Wob + (size_t)(n0 + l16) * 256 + k0 + q * 8);
      pa0 = __builtin_amdgcn_mfma_f32_16x16x32_bf16(a, b, pa0, 0, 0, 0);
    }
#pragma unroll
    for (int k0 = 128; k0 < 256; k0 += 32) {
      short8 a = *(const short8*)&obls[l16][k0 + q * 8];
      short8 b = *(const short8*)(Wob + (size_t)(n0 + l16) * 256 + k0 + q * 8);
      pa1 = __builtin_amdgcn_mfma_f32_16x16x32_bf16(a, b, pa1, 0, 0, 0);
    }
    f32x4 pacc = pa0 + pa1;
    const int col = n0 + l16;
    const float bia = bo[col];
#pragma unroll
    for (int r = 0; r < 4; ++r) {
      out[(size_t)(row0 + q * 4 + r) * 256 + col] = pacc[r] + bia;
    }
  }
}

// ===========================================================================
extern "C" void kernel_launch(void* const* d_in, const int* in_sizes, int n_in,
                              void* d_out, int out_size, void* d_ws, size_t ws_size,
                              hipStream_t stream) {
  const float* h_target = (const float*)d_in[0];
  const float* h_neigh  = (const float*)d_in[1];
  const int*   adjacency= (const int*)d_in[2];
  const int*   edge_ty  = (const int*)d_in[3];
  const float* Wq = (const float*)d_in[4];
  const float* bq = (const float*)d_in[5];
  const float* Wk = (const float*)d_in[6];
  const float* bk = (const float*)d_in[7];
  const float* Wv = (const float*)d_in[8];
  const float* bv = (const float*)d_in[9];
  const float* Wo = (const float*)d_in[10];
  const float* bo = (const float*)d_in[11];
  const float* E  = (const float*)d_in[12];
  float* out = (float*)d_out;

  unsigned char* wsb = (unsigned char*)d_ws;
  unsigned char*  tags = wsb;                                  // 1 MB
  unsigned short* Qh  = (unsigned short*)(wsb + 0x100000);     // 512 KB
  unsigned short* Kh  = (unsigned short*)(wsb + 0x180000);     // 512 KB
  unsigned short* Vt  = (unsigned short*)(wsb + 0x200000);     // 512 KB
  unsigned short* Wob = (unsigned short*)(wsb + 0x280000);     // 128 KB
  float* ek = (float*)(wsb + 0x2A0000);                        // 2 KB
  float* ev = (float*)(wsb + 0x2A0800);                        // 2 KB

  fused_prep_qkv<<<1056, 256, 0, stream>>>(
      h_target, h_neigh, adjacency, edge_ty, Wq, bq, Wk, bk, Wv, bv, Wo, E,
      tags, ek, ev, Qh, Kh, Vt, Wob);
  attn_proj<<<64, 1024, 0, stream>>>(Qh, Kh, Vt, ek, ev, tags, Wob, bo, out);
}

// Round 10
// 104.501 us; speedup vs baseline: 1.2819x; 1.2819x over previous
//
#include <hip/hip_runtime.h>
#include <math.h>

#define BT 1024
#define BN 1024
#define D  256
#define H  8
#define DH 32

typedef __attribute__((ext_vector_type(8))) short short8;
typedef __attribute__((ext_vector_type(4))) float f32x4;

__device__ __forceinline__ unsigned short f2bf(float x) {
  union { float f; unsigned int u; } v; v.f = x;
  unsigned int r = v.u + 0x7fffu + ((v.u >> 16) & 1u);
  return (unsigned short)(r >> 16);
}
__device__ __forceinline__ float bf2f(unsigned short u) {
  union { unsigned int u; float f; } v; v.u = ((unsigned int)u) << 16;
  return v.f;
}
__device__ __forceinline__ unsigned pack2(float a, float b) {
  return (unsigned)f2bf(a) | ((unsigned)f2bf(b) << 16);
}

// ===========================================================================
// Dispatch 1: blocks [0,384)   qkv GEMMs, 32x64 tiles (fp32->bf16 in LDS)
//             blocks [384,640) tag pack -> tagsP[rt][nq][row][r] (quad layout)
//             blocks [640,656) ek/ev = E @ {Wk,Wv}^T
//             blocks [656,672) Wo fp32 -> bf16
// tagsP element (global row R, neighbor n) lives at
//   ((R>>4)*256 + (n>>2))*64 + (R&15)*4 + (n&3)
// so an attn wave's uchar4 load (fixed nq, rows 0..15) is one 64 B span.
// ===========================================================================
__global__ __launch_bounds__(256) void fused_prep_qkv(
    const float* __restrict__ ht, const float* __restrict__ hn,
    const int* __restrict__ adj, const int* __restrict__ ety,
    const float* __restrict__ Wq, const float* __restrict__ bq,
    const float* __restrict__ Wk, const float* __restrict__ bk,
    const float* __restrict__ Wv, const float* __restrict__ bv,
    const float* __restrict__ Wo, const float* __restrict__ E,
    unsigned char* __restrict__ tagsP, float* __restrict__ ek,
    float* __restrict__ ev, unsigned short* __restrict__ Qh,
    unsigned short* __restrict__ Kh, unsigned short* __restrict__ Vt,
    unsigned short* __restrict__ Wob) {
  const int blk = blockIdx.x;
  const int tid = threadIdx.x;

  if (blk < 384) {
    // ---------------- qkv GEMM, 32 rows x 64 cols per block ----------------
    const int gm = blk >> 7;           // 0=Q, 1=K, 2=V (128 jobs each)
    const int rem = blk & 127;
    const int m0 = (rem & 31) * 32;    // M strip (32 rows)
    const int nb0 = (rem >> 5) * 64;   // N group
    const float* X = (gm == 0) ? ht : hn;
    const float* W = (gm == 0) ? Wq : (gm == 1) ? Wk : Wv;
    const float* bias = (gm == 0) ? bq : (gm == 1) ? bk : bv;

    __shared__ unsigned short als[32][264];
    __shared__ unsigned short bls[64][264];

    const int c = (tid & 15) * 16;
#pragma unroll
    for (int j = 0; j < 2; ++j) {
      int row = j * 16 + (tid >> 4);
      const float* s = X + (size_t)(m0 + row) * D + c;
      uint4 u0, u1;
      float4 f;
      f = *(const float4*)(s + 0);  u0.x = pack2(f.x, f.y); u0.y = pack2(f.z, f.w);
      f = *(const float4*)(s + 4);  u0.z = pack2(f.x, f.y); u0.w = pack2(f.z, f.w);
      f = *(const float4*)(s + 8);  u1.x = pack2(f.x, f.y); u1.y = pack2(f.z, f.w);
      f = *(const float4*)(s + 12); u1.z = pack2(f.x, f.y); u1.w = pack2(f.z, f.w);
      *(uint4*)&als[row][c] = u0;
      *(uint4*)&als[row][c + 8] = u1;
    }
#pragma unroll
    for (int j = 0; j < 4; ++j) {
      int row = j * 16 + (tid >> 4);
      const float* s = W + (size_t)(nb0 + row) * D + c;
      uint4 u0, u1;
      float4 f;
      f = *(const float4*)(s + 0);  u0.x = pack2(f.x, f.y); u0.y = pack2(f.z, f.w);
      f = *(const float4*)(s + 4);  u0.z = pack2(f.x, f.y); u0.w = pack2(f.z, f.w);
      f = *(const float4*)(s + 8);  u1.x = pack2(f.x, f.y); u1.y = pack2(f.z, f.w);
      f = *(const float4*)(s + 12); u1.z = pack2(f.x, f.y); u1.w = pack2(f.z, f.w);
      *(uint4*)&bls[row][c] = u0;
      *(uint4*)&bls[row][c + 8] = u1;
    }
    __syncthreads();

    const int lane = tid & 63, wid = tid >> 6;
    const int quad = lane >> 4, l16 = lane & 15;
    f32x4 aA0 = {0.f,0.f,0.f,0.f}, aA1 = {0.f,0.f,0.f,0.f};
    f32x4 aB0 = {0.f,0.f,0.f,0.f}, aB1 = {0.f,0.f,0.f,0.f};
#pragma unroll
    for (int k0 = 0; k0 < 128; k0 += 32) {
      short8 a0 = *(const short8*)&als[l16][k0 + quad * 8];
      short8 a1 = *(const short8*)&als[16 + l16][k0 + quad * 8];
      short8 b = *(const short8*)&bls[wid * 16 + l16][k0 + quad * 8];
      aA0 = __builtin_amdgcn_mfma_f32_16x16x32_bf16(a0, b, aA0, 0, 0, 0);
      aB0 = __builtin_amdgcn_mfma_f32_16x16x32_bf16(a1, b, aB0, 0, 0, 0);
    }
#pragma unroll
    for (int k0 = 128; k0 < 256; k0 += 32) {
      short8 a0 = *(const short8*)&als[l16][k0 + quad * 8];
      short8 a1 = *(const short8*)&als[16 + l16][k0 + quad * 8];
      short8 b = *(const short8*)&bls[wid * 16 + l16][k0 + quad * 8];
      aA1 = __builtin_amdgcn_mfma_f32_16x16x32_bf16(a0, b, aA1, 0, 0, 0);
      aB1 = __builtin_amdgcn_mfma_f32_16x16x32_bf16(a1, b, aB1, 0, 0, 0);
    }
    f32x4 accA = aA0 + aA1;
    f32x4 accB = aB0 + aB1;

    const int col = nb0 + wid * 16 + l16;
    const float bia = bias[col];
    const int h = col >> 5, d = col & 31;
    if (gm == 2) {
      uint2 o0, o1;
      o0.x = pack2(accA[0] + bia, accA[1] + bia);
      o0.y = pack2(accA[2] + bia, accA[3] + bia);
      o1.x = pack2(accB[0] + bia, accB[1] + bia);
      o1.y = pack2(accB[2] + bia, accB[3] + bia);
      *(uint2*)(Vt + (size_t)h * 32768 + (size_t)d * 1024 + m0 + quad * 4) = o0;
      *(uint2*)(Vt + (size_t)h * 32768 + (size_t)d * 1024 + m0 + 16 + quad * 4) = o1;
    } else {
      unsigned short* dst = (gm == 0) ? Qh : Kh;
#pragma unroll
      for (int r = 0; r < 4; ++r) {
        int row = m0 + quad * 4 + r;
        dst[(size_t)h * 32768 + (size_t)row * 32 + d] = f2bf(accA[r] + bia);
        dst[(size_t)h * 32768 + (size_t)(row + 16) * 32 + d] = f2bf(accB[r] + bia);
      }
    }
  } else if (blk < 640) {
    // ---------------- tag pack into quad layout ----------------
    const int local = blk - 384;
    __shared__ unsigned char tl[64][68];
    const int row0t = (local >> 4) * 64;
    const int n0 = (local & 15) * 64;
#pragma unroll
    for (int j = 0; j < 4; ++j) {
      int row = j * 16 + (tid >> 4);
      int c0 = (tid & 15) * 4;
      int4 a = *(const int4*)(adj + (size_t)(row0t + row) * BN + n0 + c0);
      int4 t = *(const int4*)(ety + (size_t)(row0t + row) * BN + n0 + c0);
      tl[row][c0 + 0] = a.x ? (unsigned char)t.x : (unsigned char)2;
      tl[row][c0 + 1] = a.y ? (unsigned char)t.y : (unsigned char)2;
      tl[row][c0 + 2] = a.z ? (unsigned char)t.z : (unsigned char)2;
      tl[row][c0 + 3] = a.w ? (unsigned char)t.w : (unsigned char)2;
    }
    __syncthreads();
    const int rt0 = row0t >> 4;
    const int nq0 = n0 >> 2;
#pragma unroll
    for (int j = 0; j < 4; ++j) {
      int idx = j * 256 + tid;
      int rt_l = idx >> 8;        // 0..3
      int rem = idx & 255;
      int nq_l = rem >> 4;        // 0..15
      int rowl = rem & 15;        // 0..15
      uchar4 v = *(const uchar4*)&tl[rt_l * 16 + rowl][nq_l * 4];
      *(uchar4*)(tagsP +
                 (((size_t)(rt0 + rt_l) * 256 + nq0 + nq_l) * 16 + rowl) * 4) = v;
    }
  } else if (blk < 656) {
    const int g = blk - 640;
    const int bx = g & 7, by = g >> 3;
    const int c = tid >> 3, kseg = tid & 7;
    const int col = bx * 32 + c;
    const float* W = by ? Wv : Wk;
    float* outp = by ? ev : ek;
    const float* wrow = W + (size_t)col * D + kseg * 32;
    const float* e0p = E + kseg * 32;
    const float* e1p = E + D + kseg * 32;
    float p0 = 0.f, p1 = 0.f;
#pragma unroll
    for (int i = 0; i < 8; ++i) {
      float4 w4 = *(const float4*)(wrow + i * 4);
      float4 a4 = *(const float4*)(e0p + i * 4);
      float4 b4 = *(const float4*)(e1p + i * 4);
      p0 += w4.x * a4.x + w4.y * a4.y + w4.z * a4.z + w4.w * a4.w;
      p1 += w4.x * b4.x + w4.y * b4.y + w4.z * b4.z + w4.w * b4.w;
    }
#pragma unroll
    for (int off = 1; off <= 4; off <<= 1) {
      p0 += __shfl_xor(p0, off);
      p1 += __shfl_xor(p1, off);
    }
    if (kseg == 0) { outp[col] = p0; outp[D + col] = p1; }
  } else {
    const int g = blk - 656;
    const int base = g * 4096;
#pragma unroll
    for (int half = 0; half < 2; ++half) {
      int e0 = base + half * 2048 + tid * 8;
      float4 f0 = *(const float4*)(Wo + e0);
      float4 f1 = *(const float4*)(Wo + e0 + 4);
      uint4 o;
      o.x = pack2(f0.x, f0.y);
      o.y = pack2(f0.z, f0.w);
      o.z = pack2(f1.x, f1.y);
      o.w = pack2(f1.z, f1.w);
      *(uint4*)(Wob + e0) = o;
    }
  }
}

// ===========================================================================
// attn (R8 structure): transposed-score MFMA, barrier-free main loop.
// Block = 8 waves x (16 rows, 1 head); wave w owns neighbors [w*128,w*128+128).
// tagsP quad layout -> each uchar4 tag load touches 4 cache lines, not 16.
// ===========================================================================
__global__ __launch_bounds__(512, 4) void attn_mfma(
    const unsigned short* __restrict__ Qh, const unsigned short* __restrict__ Kh,
    const unsigned short* __restrict__ Vt,
    const float* __restrict__ ek, const float* __restrict__ ev,
    const unsigned char* __restrict__ tagsP, unsigned short* __restrict__ Ob) {
  __shared__ __align__(16) unsigned short P[8][16][40];
  __shared__ float comb[8 * 64 * 11];

  const int h = blockIdx.y;
  const int rt = blockIdx.x;
  const int row0 = rt * 16;
  const int tid = threadIdx.x;
  const int w = tid >> 6;
  const int lane = tid & 63;
  const int q = lane >> 4, l16 = lane & 15;
  const float scale = 0.17677669529663687f;  // 1/sqrt(32)

  const unsigned short* Qbase = Qh + (size_t)h * 32768;
  const unsigned short* Kbase = Kh + (size_t)h * 32768;
  const unsigned short* Vbase = Vt + (size_t)h * 32768;
  const unsigned char* tagb = tagsP + (size_t)rt * 16384;

  short8 bQ = *(const short8*)(Qbase + (size_t)(row0 + l16) * 32 + q * 8);

  float qe_mine = 0.f;
  {
    int r = (lane >> 1) & 15, tg = lane & 1;
    const unsigned short* qp = Qbase + (size_t)(row0 + r) * 32;
    const float* ep = ek + tg * D + h * DH;
#pragma unroll
    for (int dd = 0; dd < 32; ++dd) qe_mine += bf2f(qp[dd]) * ep[dd];
    qe_mine *= scale;
  }
  const float qe0 = __shfl(qe_mine, l16 * 2, 64);
  const float qe1 = __shfl(qe_mine, l16 * 2 + 1, 64);

  float den_loc = 0.f, s1_loc = 0.f;
  f32x4 acc0 = {0.f, 0.f, 0.f, 0.f};
  f32x4 acc1 = {0.f, 0.f, 0.f, 0.f};
  const f32x4 zero = {0.f, 0.f, 0.f, 0.f};
  unsigned short* Pw = &P[w][0][0];

  for (int cch = 0; cch < 4; ++cch) {
    const int nb = w * 128 + cch * 32;
    short8 aK0 = *(const short8*)(Kbase + (size_t)(nb + l16) * 32 + q * 8);
    short8 aK1 = *(const short8*)(Kbase + (size_t)(nb + 16 + l16) * 32 + q * 8);
    short8 vA0 = *(const short8*)(Vbase + (size_t)l16 * 1024 + nb + q * 8);
    short8 vA1 = *(const short8*)(Vbase + (size_t)(16 + l16) * 1024 + nb + q * 8);
    uchar4 t0 = *(const uchar4*)(tagb + ((nb >> 2) + q) * 64 + l16 * 4);
    uchar4 t1 = *(const uchar4*)(tagb + ((nb >> 2) + q + 4) * 64 + l16 * 4);

    f32x4 sc0 = __builtin_amdgcn_mfma_f32_16x16x32_bf16(aK0, bQ, zero, 0, 0, 0);
    f32x4 sc1 = __builtin_amdgcn_mfma_f32_16x16x32_bf16(aK1, bQ, zero, 0, 0, 0);

    const unsigned char ta0[4] = {t0.x, t0.y, t0.z, t0.w};
    const unsigned char ta1[4] = {t1.x, t1.y, t1.z, t1.w};
    float e0[4], e1[4];
#pragma unroll
    for (int r = 0; r < 4; ++r) {
      const int tg = ta0[r];
      float e = 0.f;
      if (tg != 2) e = __expf(fmaf(sc0[r], scale, tg ? qe1 : qe0));
      e0[r] = e;
      den_loc += e;
      s1_loc += (tg == 1) ? e : 0.f;
    }
#pragma unroll
    for (int r = 0; r < 4; ++r) {
      const int tg = ta1[r];
      float e = 0.f;
      if (tg != 2) e = __expf(fmaf(sc1[r], scale, tg ? qe1 : qe0));
      e1[r] = e;
      den_loc += e;
      s1_loc += (tg == 1) ? e : 0.f;
    }
    uint2 w0, w1;
    w0.x = pack2(e0[0], e0[1]); w0.y = pack2(e0[2], e0[3]);
    w1.x = pack2(e1[0], e1[1]); w1.y = pack2(e1[2], e1[3]);
    *(uint2*)&Pw[l16 * 40 + q * 4] = w0;
    *(uint2*)&Pw[l16 * 40 + 16 + q * 4] = w1;
    short8 pB = *(const short8*)&Pw[l16 * 40 + q * 8];
    acc0 = __builtin_amdgcn_mfma_f32_16x16x32_bf16(vA0, pB, acc0, 0, 0, 0);
    acc1 = __builtin_amdgcn_mfma_f32_16x16x32_bf16(vA1, pB, acc1, 0, 0, 0);
  }

  den_loc += __shfl_xor(den_loc, 16);
  den_loc += __shfl_xor(den_loc, 32);
  s1_loc += __shfl_xor(s1_loc, 16);
  s1_loc += __shfl_xor(s1_loc, 32);

  {
    float* cw = &comb[(w * 64 + lane) * 11];
    cw[0] = acc0[0]; cw[1] = acc0[1]; cw[2] = acc0[2]; cw[3] = acc0[3];
    cw[4] = acc1[0]; cw[5] = acc1[1]; cw[6] = acc1[2]; cw[7] = acc1[3];
    cw[8] = den_loc; cw[9] = s1_loc;
  }
  __syncthreads();
  if (w == 0) {
    float a0[4] = {0.f, 0.f, 0.f, 0.f}, a1[4] = {0.f, 0.f, 0.f, 0.f};
    float dn = 0.f, s1 = 0.f;
#pragma unroll
    for (int ww = 0; ww < 8; ++ww) {
      const float* cr = &comb[(ww * 64 + lane) * 11];
#pragma unroll
      for (int r = 0; r < 4; ++r) { a0[r] += cr[r]; a1[r] += cr[4 + r]; }
      dn += cr[8];
      s1 += cr[9];
    }
    const float s0 = dn - s1;
    const float inv = dn > 0.f ? 1.f / dn : 0.f;
    const float4 ev0a = *(const float4*)(ev + h * DH + q * 4);
    const float4 ev1a = *(const float4*)(ev + D + h * DH + q * 4);
    const float4 ev0b = *(const float4*)(ev + h * DH + 16 + q * 4);
    const float4 ev1b = *(const float4*)(ev + D + h * DH + 16 + q * 4);
    float oa[4], ob[4];
    oa[0] = (a0[0] + s1 * ev1a.x + s0 * ev0a.x) * inv;
    oa[1] = (a0[1] + s1 * ev1a.y + s0 * ev0a.y) * inv;
    oa[2] = (a0[2] + s1 * ev1a.z + s0 * ev0a.z) * inv;
    oa[3] = (a0[3] + s1 * ev1a.w + s0 * ev0a.w) * inv;
    ob[0] = (a1[0] + s1 * ev1b.x + s0 * ev0b.x) * inv;
    ob[1] = (a1[1] + s1 * ev1b.y + s0 * ev0b.y) * inv;
    ob[2] = (a1[2] + s1 * ev1b.z + s0 * ev0b.z) * inv;
    ob[3] = (a1[3] + s1 * ev1b.w + s0 * ev0b.w) * inv;
    uint2 u0, u1;
    u0.x = pack2(oa[0], oa[1]); u0.y = pack2(oa[2], oa[3]);
    u1.x = pack2(ob[0], ob[1]); u1.y = pack2(ob[2], ob[3]);
    unsigned short* dst = Ob + (size_t)(row0 + l16) * D + h * DH + q * 4;
    *(uint2*)dst = u0;
    *(uint2*)(dst + 16) = u1;
  }
}

// ===========================================================================
// out = Ob @ Wob^T + bo (fp32 out). Direct global frags, no LDS. grid (64,4).
// ===========================================================================
__global__ __launch_bounds__(256) void proj_out_mfma(
    const unsigned short* __restrict__ Ob, const unsigned short* __restrict__ Wob,
    const float* __restrict__ bo, float* __restrict__ out) {
  const int lane = threadIdx.x & 63;
  const int wid = threadIdx.x >> 6;
  const int quad = lane >> 4, l16 = lane & 15;
  const int m0 = blockIdx.x * 16;
  const int n0 = blockIdx.y * 64 + wid * 16;
  f32x4 acc0 = {0.f, 0.f, 0.f, 0.f};
  f32x4 acc1 = {0.f, 0.f, 0.f, 0.f};
#pragma unroll
  for (int k0 = 0; k0 < 128; k0 += 32) {
    short8 a = *(const short8*)(Ob + (size_t)(m0 + l16) * 256 + k0 + quad * 8);
    short8 b = *(const short8*)(Wob + (size_t)(n0 + l16) * 256 + k0 + quad * 8);
    acc0 = __builtin_amdgcn_mfma_f32_16x16x32_bf16(a, b, acc0, 0, 0, 0);
  }
#pragma unroll
  for (int k0 = 128; k0 < 256; k0 += 32) {
    short8 a = *(const short8*)(Ob + (size_t)(m0 + l16) * 256 + k0 + quad * 8);
    short8 b = *(const short8*)(Wob + (size_t)(n0 + l16) * 256 + k0 + quad * 8);
    acc1 = __builtin_amdgcn_mfma_f32_16x16x32_bf16(a, b, acc1, 0, 0, 0);
  }
  f32x4 acc = acc0 + acc1;
  const int col = n0 + l16;
  const float bia = bo[col];
#pragma unroll
  for (int r = 0; r < 4; ++r) {
    out[(size_t)(m0 + quad * 4 + r) * 256 + col] = acc[r] + bia;
  }
}

// ===========================================================================
extern "C" void kernel_launch(void* const* d_in, const int* in_sizes, int n_in,
                              void* d_out, int out_size, void* d_ws, size_t ws_size,
                              hipStream_t stream) {
  const float* h_target = (const float*)d_in[0];
  const float* h_neigh  = (const float*)d_in[1];
  const int*   adjacency= (const int*)d_in[2];
  const int*   edge_ty  = (const int*)d_in[3];
  const float* Wq = (const float*)d_in[4];
  const float* bq = (const float*)d_in[5];
  const float* Wk = (const float*)d_in[6];
  const float* bk = (const float*)d_in[7];
  const float* Wv = (const float*)d_in[8];
  const float* bv = (const float*)d_in[9];
  const float* Wo = (const float*)d_in[10];
  const float* bo = (const float*)d_in[11];
  const float* E  = (const float*)d_in[12];
  float* out = (float*)d_out;

  unsigned char* wsb = (unsigned char*)d_ws;
  unsigned char*  tagsP = wsb;                                 // 1 MB
  unsigned short* Qh  = (unsigned short*)(wsb + 0x100000);     // 512 KB
  unsigned short* Kh  = (unsigned short*)(wsb + 0x180000);     // 512 KB
  unsigned short* Vt  = (unsigned short*)(wsb + 0x200000);     // 512 KB
  unsigned short* Ob  = (unsigned short*)(wsb + 0x280000);     // 512 KB
  unsigned short* Wob = (unsigned short*)(wsb + 0x300000);     // 128 KB
  float* ek = (float*)(wsb + 0x320000);                        // 2 KB
  float* ev = (float*)(wsb + 0x320800);                        // 2 KB

  fused_prep_qkv<<<672, 256, 0, stream>>>(
      h_target, h_neigh, adjacency, edge_ty, Wq, bq, Wk, bk, Wv, bv, Wo, E,
      tagsP, ek, ev, Qh, Kh, Vt, Wob);
  attn_mfma<<<dim3(64, 8), 512, 0, stream>>>(Qh, Kh, Vt, ek, ev, tagsP, Ob);
  proj_out_mfma<<<dim3(64, 4), 256, 0, stream>>>(Ob, Wob, bo, out);
}